// Round 4
// baseline (494.440 us; speedup 1.0000x reference)
//
#include <hip/hip_runtime.h>
#include <float.h>

#define D 64
#define MARGIN 6e-5f

typedef float f32x4 __attribute__((ext_vector_type(4)));
typedef short bf16x8 __attribute__((ext_vector_type(8)));

// ---- bf16 round-to-nearest-even split helpers (bit-level)
__device__ __forceinline__ unsigned short bf16_rn(float f) {
  unsigned int u = __float_as_uint(f);
  u += 0x7fffu + ((u >> 16) & 1u);
  return (unsigned short)(u >> 16);
}
__device__ __forceinline__ float bf16_to_f(unsigned short h) {
  return __uint_as_float(((unsigned int)h) << 16);
}

// numpy pairwise_sum (n=64): 8 stride-interleaved accumulators, tree combine;
// squares rounded separately. Verified bit-exact vs np in rounds 2-3.
__device__ __forceinline__ float np_sum_sq_64(const float* v) {
  float s[8];
#pragma unroll
  for (int j = 0; j < 8; ++j) s[j] = __fmul_rn(v[j], v[j]);
#pragma unroll
  for (int b = 1; b < 8; ++b) {
#pragma unroll
    for (int j = 0; j < 8; ++j)
      s[j] = __fadd_rn(s[j], __fmul_rn(v[8 * b + j], v[8 * b + j]));
  }
  float t01 = __fadd_rn(s[0], s[1]);
  float t23 = __fadd_rn(s[2], s[3]);
  float t45 = __fadd_rn(s[4], s[5]);
  float t67 = __fadd_rn(s[6], s[7]);
  return __fadd_rn(__fadd_rn(t01, t23), __fadd_rn(t45, t67));
}

// ---------------- Kernel A: c2[k] np-faithful + bf16 hi/lo codebook split
__global__ __launch_bounds__(256) void vq_prep(
    const float* __restrict__ cb, unsigned short* __restrict__ cbh,
    unsigned short* __restrict__ cbl, float* __restrict__ c2,
    unsigned int* __restrict__ flag_count, int K) {
  if (blockIdx.x == 0 && threadIdx.x == 0) *flag_count = 0u;
  int k = blockIdx.x * 256 + threadIdx.x;
  if (k >= K) return;
  float row[D];
  const float4* cp = (const float4*)(cb + (size_t)k * D);
#pragma unroll
  for (int i = 0; i < 16; ++i) {
    float4 v = cp[i];
    row[4 * i] = v.x; row[4 * i + 1] = v.y;
    row[4 * i + 2] = v.z; row[4 * i + 3] = v.w;
  }
#pragma unroll
  for (int i = 0; i < 16; ++i) {
    unsigned short h[4], l[4];
#pragma unroll
    for (int e = 0; e < 4; ++e) {
      float f = row[4 * i + e];
      h[e] = bf16_rn(f);
      l[e] = bf16_rn(f - bf16_to_f(h[e]));
    }
    *(uint2*)(cbh + (size_t)k * D + 4 * i) =
        make_uint2((unsigned int)h[0] | ((unsigned int)h[1] << 16),
                   (unsigned int)h[2] | ((unsigned int)h[3] << 16));
    *(uint2*)(cbl + (size_t)k * D + 4 * i) =
        make_uint2((unsigned int)l[0] | ((unsigned int)l[1] << 16),
                   (unsigned int)l[2] | ((unsigned int)l[3] << 16));
  }
  c2[k] = np_sum_sq_64(row);
}

// ---------------- Kernel B: MFMA screen + fused gather.
// wg=256 (4 waves) x 64 rows; 16 chunks of 64 codes; B-chunk software-pipelined.
__global__ __launch_bounds__(256) void vq_screen(
    const float* __restrict__ residual, const float* __restrict__ codebook,
    const unsigned short* __restrict__ cbh, const unsigned short* __restrict__ cbl,
    const float* __restrict__ c2, float* __restrict__ out_q,
    float* __restrict__ codes_f, unsigned int* __restrict__ flag_count,
    int* __restrict__ flag_list, int N, int K) {
  __shared__ unsigned short smem[8192];  // 16 KB
  unsigned short* ldsAh = smem;
  unsigned short* ldsAl = smem + 4096;

  int tid = threadIdx.x;
  int rowbase = blockIdx.x * 64;

  // ---- stage 64 rows: fp32 -> hi/lo bf16, fragment-permuted (verified layout)
  for (int i = tid; i < 1024; i += 256) {
    int r = i >> 4, d0 = (i & 15) * 4;
    float4 v = *(const float4*)(residual + (size_t)(rowbase + r) * D + d0);
    float vf[4] = {v.x, v.y, v.z, v.w};
    unsigned short h[4], l[4];
#pragma unroll
    for (int e = 0; e < 4; ++e) {
      h[e] = bf16_rn(vf[e]);
      l[e] = bf16_rn(vf[e] - bf16_to_f(h[e]));
    }
    int tile = r >> 4, rr = r & 15;
    int kblk = d0 >> 5, kk = d0 & 31;
    int lanep = rr + 16 * (kk >> 3);
    int off = ((tile * 2 + kblk) * 64 + lanep) * 8 + (kk & 7);
    *(uint2*)(ldsAh + off) = make_uint2((unsigned int)h[0] | ((unsigned int)h[1] << 16),
                                        (unsigned int)h[2] | ((unsigned int)h[3] << 16));
    *(uint2*)(ldsAl + off) = make_uint2((unsigned int)l[0] | ((unsigned int)l[1] << 16),
                                        (unsigned int)l[2] | ((unsigned int)l[3] << 16));
  }
  __syncthreads();

  int w = tid >> 6, lane = tid & 63;
  int lane15 = lane & 15, lq = lane >> 4;

  // A fragments -> registers (ds_read_b128, conflict-free)
  bf16x8 ah[4][2], al[4][2];
#pragma unroll
  for (int t = 0; t < 4; ++t)
#pragma unroll
    for (int kb = 0; kb < 2; ++kb) {
      ah[t][kb] = *(const bf16x8*)(ldsAh + ((t * 2 + kb) * 64 + lane) * 8);
      al[t][kb] = *(const bf16x8*)(ldsAl + ((t * 2 + kb) * 64 + lane) * 8);
    }

  float m1[4][4], m2[4][4];
  int bi[4][4];
#pragma unroll
  for (int t = 0; t < 4; ++t)
#pragma unroll
    for (int j = 0; j < 4; ++j) { m1[t][j] = FLT_MAX; m2[t][j] = FLT_MAX; bi[t][j] = 0; }

  int code = w * 16 + lane15;
  const unsigned short* ph = cbh + (size_t)code * D + lq * 8;
  const unsigned short* pl = cbl + (size_t)code * D + lq * 8;

  // prime the pipeline: chunk 0 B-fragments + c2
  bf16x8 Bh0 = *(const bf16x8*)(ph);
  bf16x8 Bh1 = *(const bf16x8*)(ph + 32);
  bf16x8 Bl0 = *(const bf16x8*)(pl);
  bf16x8 Bl1 = *(const bf16x8*)(pl + 32);
  float Bc2 = c2[code];

  for (int cc = 0; cc < 16; ++cc) {
    bf16x8 ch0 = Bh0, ch1 = Bh1, cl0 = Bl0, cl1 = Bl1;
    float c2v = Bc2;
    int curcode = code;

    if (cc < 15) {  // prefetch next chunk while MFMAs run
      ph += 64 * D; pl += 64 * D; code += 64;
      Bh0 = *(const bf16x8*)(ph);
      Bh1 = *(const bf16x8*)(ph + 32);
      Bl0 = *(const bf16x8*)(pl);
      Bl1 = *(const bf16x8*)(pl + 32);
      Bc2 = c2[code];
    }

#pragma unroll
    for (int t = 0; t < 4; ++t) {
      f32x4 a = {0.f, 0.f, 0.f, 0.f};
      a = __builtin_amdgcn_mfma_f32_16x16x32_bf16(ah[t][0], ch0, a, 0, 0, 0);
      a = __builtin_amdgcn_mfma_f32_16x16x32_bf16(ah[t][1], ch1, a, 0, 0, 0);
      a = __builtin_amdgcn_mfma_f32_16x16x32_bf16(al[t][0], ch0, a, 0, 0, 0);
      a = __builtin_amdgcn_mfma_f32_16x16x32_bf16(al[t][1], ch1, a, 0, 0, 0);
      a = __builtin_amdgcn_mfma_f32_16x16x32_bf16(ah[t][0], cl0, a, 0, 0, 0);
      a = __builtin_amdgcn_mfma_f32_16x16x32_bf16(ah[t][1], cl1, a, 0, 0, 0);
#pragma unroll
      for (int j = 0; j < 4; ++j) {
        float s = __builtin_fmaf(-2.f, a[j], c2v);
        bool lt = s < m1[t][j];
        m2[t][j] = fminf(m2[t][j], fmaxf(m1[t][j], s));
        m1[t][j] = lt ? s : m1[t][j];
        bi[t][j] = lt ? curcode : bi[t][j];
      }
    }
  }

  // reduce across the 16 code-columns (lanes differing in bits 0..3)
#pragma unroll
  for (int dlt = 1; dlt < 16; dlt <<= 1) {
#pragma unroll
    for (int t = 0; t < 4; ++t)
#pragma unroll
      for (int j = 0; j < 4; ++j) {
        float om1 = __shfl_xor(m1[t][j], dlt, 64);
        float om2 = __shfl_xor(m2[t][j], dlt, 64);
        int obi = __shfl_xor(bi[t][j], dlt, 64);
        float nm2 = fminf(fminf(m2[t][j], om2), fmaxf(m1[t][j], om1));
        bool take = (om1 < m1[t][j]) || (om1 == m1[t][j] && obi < bi[t][j]);
        m1[t][j] = take ? om1 : m1[t][j];
        bi[t][j] = take ? obi : bi[t][j];
        m2[t][j] = nm2;
      }
  }

  __syncthreads();  // A-LDS no longer needed; reuse front 3 KB for cross-wave reduce
  float* red = (float*)smem;          // [wave][row(64)][3] = 768 floats
  int* code_lds = ((int*)smem) + 1024;  // disjoint area (bytes 4096..4351)
  if (lane15 == 0) {
#pragma unroll
    for (int t = 0; t < 4; ++t)
#pragma unroll
      for (int j = 0; j < 4; ++j) {
        int r = t * 16 + lq * 4 + j;
        red[(w * 64 + r) * 3 + 0] = m1[t][j];
        red[(w * 64 + r) * 3 + 1] = m2[t][j];
        red[(w * 64 + r) * 3 + 2] = __int_as_float(bi[t][j]);
      }
  }
  __syncthreads();
  if (tid < 64) {
    float M1 = FLT_MAX, M2 = FLT_MAX;
    int BI = 0x7fffffff;
#pragma unroll
    for (int wv = 0; wv < 4; ++wv) {
      float om1 = red[(wv * 64 + tid) * 3 + 0];
      float om2 = red[(wv * 64 + tid) * 3 + 1];
      int obi = __float_as_int(red[(wv * 64 + tid) * 3 + 2]);
      float nm2 = fminf(fminf(M2, om2), fmaxf(M1, om1));
      bool take = (om1 < M1) || (om1 == M1 && obi < BI);
      M1 = take ? om1 : M1;
      BI = take ? obi : BI;
      M2 = nm2;
    }
    codes_f[rowbase + tid] = (float)BI;
    code_lds[tid] = BI;
    if (M2 - M1 < MARGIN) {
      unsigned int s = atomicAdd(flag_count, 1u);
      flag_list[s] = rowbase + tid;
    }
  }
  __syncthreads();

  // ---- fused gather: quantized rows for this block (codes broadcast from LDS)
  for (int e = tid; e < 4096; e += 256) {
    int r = e >> 6, d = e & 63;  // r is wave-uniform per iteration
    out_q[(size_t)rowbase * D + e] = codebook[((size_t)code_lds[r] << 6) + d];
  }
}

// ---------------- Kernel C: exact np-faithful rescore of flagged rows (+fix out_q).
// One wave per row; 2 independent chains/lane for latency; per-code dot stays
// the exact sequential fp32 FMA chain (np-faithful).
__global__ __launch_bounds__(256) void vq_rescore(
    const float* __restrict__ residual, const float* __restrict__ codebook,
    const float* __restrict__ c2, float* __restrict__ codes_f,
    float* __restrict__ out_q, const unsigned int* __restrict__ flag_count,
    const int* __restrict__ flag_list, int K) {
  unsigned int cnt = *flag_count;
  int wv = threadIdx.x >> 6, lane = threadIdx.x & 63;
  for (unsigned int j = blockIdx.x * 4 + wv; j < cnt; j += gridDim.x * 4) {
    int n = flag_list[j];
    float rr[D];
    const float4* rp = (const float4*)(residual + (size_t)n * D);
#pragma unroll
    for (int i = 0; i < 16; ++i) {
      float4 v = rp[i];
      rr[4 * i] = v.x; rr[4 * i + 1] = v.y; rr[4 * i + 2] = v.z; rr[4 * i + 3] = v.w;
    }
    float r2 = np_sum_sq_64(rr);
    float b1 = FLT_MAX, b2 = FLT_MAX;
    int k1 = 0, k2 = 0;
    for (int q = 0; q < 8; ++q) {
      int ka = lane + 64 * q;        // chain A: codes < 512
      int kb = ka + 512;             // chain B: codes >= 512
      const float* ca = codebook + (size_t)ka * D;
      const float* cb = codebook + (size_t)kb * D;
      float ma = 0.f, mb = 0.f;
#pragma unroll
      for (int d = 0; d < D; ++d) {
        ma = __fmaf_rn(rr[d], ca[d], ma);
        mb = __fmaf_rn(rr[d], cb[d], mb);
      }
      float da = __fsub_rn(__fadd_rn(r2, c2[ka]), __fmul_rn(2.0f, ma));
      float db = __fsub_rn(__fadd_rn(r2, c2[kb]), __fmul_rn(2.0f, mb));
      if (da < b1) { b1 = da; k1 = ka; }
      if (db < b2) { b2 = db; k2 = kb; }
    }
    if (b2 < b1) { b1 = b2; k1 = k2; }  // strict: lower-index chain wins ties
#pragma unroll
    for (int off = 32; off > 0; off >>= 1) {
      float ob = __shfl_down(b1, off, 64);
      int oi = __shfl_down(k1, off, 64);
      if (ob < b1 || (ob == b1 && oi < k1)) { b1 = ob; k1 = oi; }
    }
    int bk = __shfl(k1, 0, 64);
    if (lane == 0) codes_f[n] = (float)bk;
    out_q[(size_t)n * D + lane] = codebook[((size_t)bk << 6) + lane];
  }
}

extern "C" void kernel_launch(void* const* d_in, const int* in_sizes, int n_in,
                              void* d_out, int out_size, void* d_ws, size_t ws_size,
                              hipStream_t stream) {
  const float* residual = (const float*)d_in[0];
  const float* codebook = (const float*)d_in[1];
  int N = in_sizes[0] / D;
  int K = in_sizes[1] / D;

  float* out_q = (float*)d_out;
  float* codes_f = out_q + (size_t)N * D;

  // ws: c2[K] | cbh[K*D] | cbl[K*D] | flag_count | flag_list[N]
  char* ws = (char*)d_ws;
  float* c2 = (float*)ws;
  unsigned short* cbh = (unsigned short*)(ws + (size_t)K * 4);
  unsigned short* cbl = (unsigned short*)(ws + (size_t)K * 4 + (size_t)K * D * 2);
  unsigned int* flag_count = (unsigned int*)(ws + (size_t)K * 4 + (size_t)K * D * 4);
  int* flag_list = (int*)(flag_count + 1);

  vq_prep<<<(K + 255) / 256, 256, 0, stream>>>(codebook, cbh, cbl, c2, flag_count, K);

  vq_screen<<<N / 64, 256, 0, stream>>>(residual, codebook, cbh, cbl, c2,
                                        out_q, codes_f, flag_count, flag_list, N, K);

  vq_rescore<<<1024, 256, 0, stream>>>(residual, codebook, c2, codes_f, out_q,
                                       flag_count, flag_list, K);
}

// Round 5
// 339.040 us; speedup vs baseline: 1.4584x; 1.4584x over previous
//
#include <hip/hip_runtime.h>
#include <float.h>

#define D 64
#define MARGIN 6e-5f

typedef float f32x4 __attribute__((ext_vector_type(4)));
typedef short bf16x8 __attribute__((ext_vector_type(8)));

// ---- bf16 round-to-nearest-even split helpers (bit-level)
__device__ __forceinline__ unsigned short bf16_rn(float f) {
  unsigned int u = __float_as_uint(f);
  u += 0x7fffu + ((u >> 16) & 1u);
  return (unsigned short)(u >> 16);
}
__device__ __forceinline__ float bf16_to_f(unsigned short h) {
  return __uint_as_float(((unsigned int)h) << 16);
}

// numpy pairwise_sum (n=64): 8 stride-interleaved accumulators, tree combine;
// squares rounded separately. Verified bit-exact vs np in rounds 2-4.
__device__ __forceinline__ float np_sum_sq_64(const float* v) {
  float s[8];
#pragma unroll
  for (int j = 0; j < 8; ++j) s[j] = __fmul_rn(v[j], v[j]);
#pragma unroll
  for (int b = 1; b < 8; ++b) {
#pragma unroll
    for (int j = 0; j < 8; ++j)
      s[j] = __fadd_rn(s[j], __fmul_rn(v[8 * b + j], v[8 * b + j]));
  }
  float t01 = __fadd_rn(s[0], s[1]);
  float t23 = __fadd_rn(s[2], s[3]);
  float t45 = __fadd_rn(s[4], s[5]);
  float t67 = __fadd_rn(s[6], s[7]);
  return __fadd_rn(__fadd_rn(t01, t23), __fadd_rn(t45, t67));
}

// ---------------- Kernel A: c2[k] np-faithful + bf16 hi/lo split + transposed cbT4
__global__ __launch_bounds__(256) void vq_prep(
    const float* __restrict__ cb, unsigned short* __restrict__ cbh,
    unsigned short* __restrict__ cbl, float4* __restrict__ cbT4,
    float* __restrict__ c2, unsigned int* __restrict__ flag_count, int K) {
  if (blockIdx.x == 0 && threadIdx.x == 0) *flag_count = 0u;
  int k = blockIdx.x * 256 + threadIdx.x;
  if (k >= K) return;
  float row[D];
  const float4* cp = (const float4*)(cb + (size_t)k * D);
#pragma unroll
  for (int i = 0; i < 16; ++i) {
    float4 v = cp[i];
    row[4 * i] = v.x; row[4 * i + 1] = v.y;
    row[4 * i + 2] = v.z; row[4 * i + 3] = v.w;
    cbT4[(size_t)i * K + k] = v;  // transposed: [d/4][k], lanes k -> coalesced
  }
#pragma unroll
  for (int i = 0; i < 16; ++i) {
    unsigned short h[4], l[4];
#pragma unroll
    for (int e = 0; e < 4; ++e) {
      float f = row[4 * i + e];
      h[e] = bf16_rn(f);
      l[e] = bf16_rn(f - bf16_to_f(h[e]));
    }
    *(uint2*)(cbh + (size_t)k * D + 4 * i) =
        make_uint2((unsigned int)h[0] | ((unsigned int)h[1] << 16),
                   (unsigned int)h[2] | ((unsigned int)h[3] << 16));
    *(uint2*)(cbl + (size_t)k * D + 4 * i) =
        make_uint2((unsigned int)l[0] | ((unsigned int)l[1] << 16),
                   (unsigned int)l[2] | ((unsigned int)l[3] << 16));
  }
  c2[k] = np_sum_sq_64(row);
}

// ---------------- Kernel B: MFMA screen + fused gather.
// wg=256 (4 waves) x 64 rows; 16 chunks of 64 codes; chunk index packed into
// low 4 mantissa bits of the score -> min-tracking needs no index registers.
__global__ __launch_bounds__(256, 3) void vq_screen(
    const float* __restrict__ residual, const float* __restrict__ codebook,
    const unsigned short* __restrict__ cbh, const unsigned short* __restrict__ cbl,
    const float* __restrict__ c2, float* __restrict__ out_q,
    float* __restrict__ codes_f, unsigned int* __restrict__ flag_count,
    int* __restrict__ flag_list, int N, int K) {
  __shared__ unsigned short smem[8192];  // 16 KB
  unsigned short* ldsAh = smem;
  unsigned short* ldsAl = smem + 4096;

  int tid = threadIdx.x;
  int rowbase = blockIdx.x * 64;

  // ---- stage 64 rows: fp32 -> hi/lo bf16, fragment-permuted (verified layout)
  for (int i = tid; i < 1024; i += 256) {
    int r = i >> 4, d0 = (i & 15) * 4;
    float4 v = *(const float4*)(residual + (size_t)(rowbase + r) * D + d0);
    float vf[4] = {v.x, v.y, v.z, v.w};
    unsigned short h[4], l[4];
#pragma unroll
    for (int e = 0; e < 4; ++e) {
      h[e] = bf16_rn(vf[e]);
      l[e] = bf16_rn(vf[e] - bf16_to_f(h[e]));
    }
    int tile = r >> 4, rr = r & 15;
    int kblk = d0 >> 5, kk = d0 & 31;
    int lanep = rr + 16 * (kk >> 3);
    int off = ((tile * 2 + kblk) * 64 + lanep) * 8 + (kk & 7);
    *(uint2*)(ldsAh + off) = make_uint2((unsigned int)h[0] | ((unsigned int)h[1] << 16),
                                        (unsigned int)h[2] | ((unsigned int)h[3] << 16));
    *(uint2*)(ldsAl + off) = make_uint2((unsigned int)l[0] | ((unsigned int)l[1] << 16),
                                        (unsigned int)l[2] | ((unsigned int)l[3] << 16));
  }
  __syncthreads();

  int w = tid >> 6, lane = tid & 63;
  int lane15 = lane & 15, lq = lane >> 4;

  // A fragments -> registers (ds_read_b128)
  bf16x8 ah[4][2], al[4][2];
#pragma unroll
  for (int t = 0; t < 4; ++t)
#pragma unroll
    for (int kb = 0; kb < 2; ++kb) {
      ah[t][kb] = *(const bf16x8*)(ldsAh + ((t * 2 + kb) * 64 + lane) * 8);
      al[t][kb] = *(const bf16x8*)(ldsAl + ((t * 2 + kb) * 64 + lane) * 8);
    }

  float m1[4][4], m2[4][4];
#pragma unroll
  for (int t = 0; t < 4; ++t)
#pragma unroll
    for (int j = 0; j < 4; ++j) { m1[t][j] = FLT_MAX; m2[t][j] = FLT_MAX; }

  const unsigned short* ph = cbh + (size_t)(w * 16 + lane15) * D + lq * 8;
  const unsigned short* pl = cbl + (size_t)(w * 16 + lane15) * D + lq * 8;
  const float* pc2 = c2 + (w * 16 + lane15);

  // prime the pipeline: chunk 0 B-fragments + c2
  bf16x8 Bh0 = *(const bf16x8*)(ph);
  bf16x8 Bh1 = *(const bf16x8*)(ph + 32);
  bf16x8 Bl0 = *(const bf16x8*)(pl);
  bf16x8 Bl1 = *(const bf16x8*)(pl + 32);
  float Bc2 = *pc2;

  for (int cc = 0; cc < 16; ++cc) {
    bf16x8 ch0 = Bh0, ch1 = Bh1, cl0 = Bl0, cl1 = Bl1;
    float c2v = Bc2;

    if (cc < 15) {  // prefetch next chunk while MFMAs run
      ph += 64 * D; pl += 64 * D; pc2 += 64;
      Bh0 = *(const bf16x8*)(ph);
      Bh1 = *(const bf16x8*)(ph + 32);
      Bl0 = *(const bf16x8*)(pl);
      Bl1 = *(const bf16x8*)(pl + 32);
      Bc2 = *pc2;
    }

#pragma unroll
    for (int t = 0; t < 4; ++t) {
      f32x4 a = {0.f, 0.f, 0.f, 0.f};
      a = __builtin_amdgcn_mfma_f32_16x16x32_bf16(ah[t][0], ch0, a, 0, 0, 0);
      a = __builtin_amdgcn_mfma_f32_16x16x32_bf16(ah[t][1], ch1, a, 0, 0, 0);
      a = __builtin_amdgcn_mfma_f32_16x16x32_bf16(al[t][0], ch0, a, 0, 0, 0);
      a = __builtin_amdgcn_mfma_f32_16x16x32_bf16(al[t][1], ch1, a, 0, 0, 0);
      a = __builtin_amdgcn_mfma_f32_16x16x32_bf16(ah[t][0], cl0, a, 0, 0, 0);
      a = __builtin_amdgcn_mfma_f32_16x16x32_bf16(ah[t][1], cl1, a, 0, 0, 0);
#pragma unroll
      for (int j = 0; j < 4; ++j) {
        float s = __builtin_fmaf(-2.f, a[j], c2v);
        // pack chunk idx into low 4 mantissa bits (<=16 ulp perturbation,
        // absorbed by MARGIN; exact ties get flagged -> rescored exactly)
        float spf = __uint_as_float((__float_as_uint(s) & 0xFFFFFFF0u) | (unsigned)cc);
        m2[t][j] = fminf(m2[t][j], fmaxf(m1[t][j], spf));
        m1[t][j] = fminf(m1[t][j], spf);
      }
    }
  }

  // unpack: cleaned score + reconstructed code
  float sc[4][4];
  int bi[4][4];
#pragma unroll
  for (int t = 0; t < 4; ++t)
#pragma unroll
    for (int j = 0; j < 4; ++j) {
      unsigned u = __float_as_uint(m1[t][j]);
      sc[t][j] = __uint_as_float(u & 0xFFFFFFF0u);
      bi[t][j] = w * 16 + lane15 + ((int)(u & 15u) << 6);
    }

  // reduce across the 16 code-columns (lanes differing in bits 0..3)
#pragma unroll
  for (int dlt = 1; dlt < 16; dlt <<= 1) {
#pragma unroll
    for (int t = 0; t < 4; ++t)
#pragma unroll
      for (int j = 0; j < 4; ++j) {
        float om1 = __shfl_xor(sc[t][j], dlt, 64);
        float om2 = __shfl_xor(m2[t][j], dlt, 64);
        int obi = __shfl_xor(bi[t][j], dlt, 64);
        float nm2 = fminf(fminf(m2[t][j], om2), fmaxf(sc[t][j], om1));
        bool take = (om1 < sc[t][j]) || (om1 == sc[t][j] && obi < bi[t][j]);
        sc[t][j] = take ? om1 : sc[t][j];
        bi[t][j] = take ? obi : bi[t][j];
        m2[t][j] = nm2;
      }
  }

  __syncthreads();  // A-LDS done; reuse for cross-wave reduce
  float* red = (float*)smem;           // [wave][row(64)][3]
  int* code_lds = ((int*)smem) + 1024; // disjoint (bytes 4096..4351)
  if (lane15 == 0) {
#pragma unroll
    for (int t = 0; t < 4; ++t)
#pragma unroll
      for (int j = 0; j < 4; ++j) {
        int r = t * 16 + lq * 4 + j;
        red[(w * 64 + r) * 3 + 0] = sc[t][j];
        red[(w * 64 + r) * 3 + 1] = m2[t][j];
        red[(w * 64 + r) * 3 + 2] = __int_as_float(bi[t][j]);
      }
  }
  __syncthreads();
  if (tid < 64) {
    float M1 = FLT_MAX, M2 = FLT_MAX;
    int BI = 0x7fffffff;
#pragma unroll
    for (int wv = 0; wv < 4; ++wv) {
      float om1 = red[(wv * 64 + tid) * 3 + 0];
      float om2 = red[(wv * 64 + tid) * 3 + 1];
      int obi = __float_as_int(red[(wv * 64 + tid) * 3 + 2]);
      float nm2 = fminf(fminf(M2, om2), fmaxf(M1, om1));
      bool take = (om1 < M1) || (om1 == M1 && obi < BI);
      M1 = take ? om1 : M1;
      BI = take ? obi : BI;
      M2 = nm2;
    }
    codes_f[rowbase + tid] = (float)BI;
    code_lds[tid] = BI;
    if (M2 - M1 < MARGIN) {
      unsigned int s = atomicAdd(flag_count, 1u);
      flag_list[s] = rowbase + tid;
    }
  }
  __syncthreads();

  // ---- fused gather
  for (int e = tid; e < 4096; e += 256) {
    int r = e >> 6, d = e & 63;
    out_q[(size_t)rowbase * D + e] = codebook[((size_t)code_lds[r] << 6) + d];
  }
}

// ---------------- Kernel C: exact np-faithful rescore, fully coalesced.
// One wave per PAIR of flagged rows; transposed codebook cbT4 -> every global
// load is 64-lane contiguous. d-outer / chunk-inner nest keeps 16 running fp32
// chains per row (np's exact sequential-d FMA order per code preserved).
__global__ __launch_bounds__(256) void vq_rescore(
    const float* __restrict__ residual, const float* __restrict__ codebook,
    const float4* __restrict__ cbT4, const float* __restrict__ c2,
    float* __restrict__ codes_f, float* __restrict__ out_q,
    const unsigned int* __restrict__ flag_count,
    const int* __restrict__ flag_list, int K) {
  unsigned int cnt = *flag_count;
  int w = threadIdx.x >> 6, lane = threadIdx.x & 63;
  unsigned int npairs = (cnt + 1) >> 1;
  for (unsigned int g = blockIdx.x * 4 + w; g < npairs; g += gridDim.x * 4) {
    int n0 = flag_list[2 * g];
    bool two = (2 * g + 1 < cnt);
    int n1 = two ? flag_list[2 * g + 1] : n0;

    float rl0 = residual[(size_t)n0 * D + lane];  // lane holds r[lane]
    float rl1 = residual[(size_t)n1 * D + lane];

    // r2 np-exact: lane j=lane&7 builds s[j] sequentially, then xor-tree 1,2,4
    int j = lane & 7;
    float x0 = __shfl(rl0, j, 64), x1 = __shfl(rl1, j, 64);
    float s0 = __fmul_rn(x0, x0), s1 = __fmul_rn(x1, x1);
#pragma unroll
    for (int b = 1; b < 8; ++b) {
      x0 = __shfl(rl0, 8 * b + j, 64);
      x1 = __shfl(rl1, 8 * b + j, 64);
      s0 = __fadd_rn(s0, __fmul_rn(x0, x0));
      s1 = __fadd_rn(s1, __fmul_rn(x1, x1));
    }
    s0 = __fadd_rn(s0, __shfl_xor(s0, 1, 64));
    s1 = __fadd_rn(s1, __shfl_xor(s1, 1, 64));
    s0 = __fadd_rn(s0, __shfl_xor(s0, 2, 64));
    s1 = __fadd_rn(s1, __shfl_xor(s1, 2, 64));
    s0 = __fadd_rn(s0, __shfl_xor(s0, 4, 64));
    s1 = __fadd_rn(s1, __shfl_xor(s1, 4, 64));
    float r2_0 = s0, r2_1 = s1;  // uniform across wave

    float m0[16], m1v[16];
#pragma unroll
    for (int ch = 0; ch < 16; ++ch) { m0[ch] = 0.f; m1v[ch] = 0.f; }

    for (int d4 = 0; d4 < 16; ++d4) {
      float a0 = __shfl(rl0, 4 * d4, 64), b0 = __shfl(rl0, 4 * d4 + 1, 64);
      float c0 = __shfl(rl0, 4 * d4 + 2, 64), e0 = __shfl(rl0, 4 * d4 + 3, 64);
      float a1 = __shfl(rl1, 4 * d4, 64), b1 = __shfl(rl1, 4 * d4 + 1, 64);
      float c1 = __shfl(rl1, 4 * d4 + 2, 64), e1 = __shfl(rl1, 4 * d4 + 3, 64);
      const float4* bp = cbT4 + (size_t)d4 * K + lane;
#pragma unroll 4
      for (int ch = 0; ch < 16; ++ch) {
        float4 c = bp[ch * 64];
        float t0 = m0[ch], t1 = m1v[ch];
        t0 = __fmaf_rn(a0, c.x, t0); t1 = __fmaf_rn(a1, c.x, t1);
        t0 = __fmaf_rn(b0, c.y, t0); t1 = __fmaf_rn(b1, c.y, t1);
        t0 = __fmaf_rn(c0, c.z, t0); t1 = __fmaf_rn(c1, c.z, t1);
        t0 = __fmaf_rn(e0, c.w, t0); t1 = __fmaf_rn(e1, c.w, t1);
        m0[ch] = t0; m1v[ch] = t1;
      }
    }

    // scores + per-lane first-min (codes ascending in ch for fixed lane)
    float best0 = FLT_MAX, best1 = FLT_MAX;
    int bk0 = 0, bk1 = 0;
#pragma unroll
    for (int ch = 0; ch < 16; ++ch) {
      int code = ch * 64 + lane;
      float c2v = c2[code];
      float d0 = __fsub_rn(__fadd_rn(r2_0, c2v), __fmul_rn(2.0f, m0[ch]));
      float d1 = __fsub_rn(__fadd_rn(r2_1, c2v), __fmul_rn(2.0f, m1v[ch]));
      if (d0 < best0) { best0 = d0; bk0 = code; }
      if (d1 < best1) { best1 = d1; bk1 = code; }
    }
    // wave argmin, tie-break smaller index (np first-index)
#pragma unroll
    for (int off = 32; off > 0; off >>= 1) {
      float ob = __shfl_down(best0, off, 64);
      int oi = __shfl_down(bk0, off, 64);
      if (ob < best0 || (ob == best0 && oi < bk0)) { best0 = ob; bk0 = oi; }
      ob = __shfl_down(best1, off, 64);
      oi = __shfl_down(bk1, off, 64);
      if (ob < best1 || (ob == best1 && oi < bk1)) { best1 = ob; bk1 = oi; }
    }
    int k0 = __shfl(bk0, 0, 64);
    int k1 = __shfl(bk1, 0, 64);
    if (lane == 0) codes_f[n0] = (float)k0;
    out_q[(size_t)n0 * D + lane] = codebook[((size_t)k0 << 6) + lane];
    if (two) {
      if (lane == 0) codes_f[n1] = (float)k1;
      out_q[(size_t)n1 * D + lane] = codebook[((size_t)k1 << 6) + lane];
    }
  }
}

extern "C" void kernel_launch(void* const* d_in, const int* in_sizes, int n_in,
                              void* d_out, int out_size, void* d_ws, size_t ws_size,
                              hipStream_t stream) {
  const float* residual = (const float*)d_in[0];
  const float* codebook = (const float*)d_in[1];
  int N = in_sizes[0] / D;
  int K = in_sizes[1] / D;

  float* out_q = (float*)d_out;
  float* codes_f = out_q + (size_t)N * D;

  // ws: c2[K] | cbh[K*D] | cbl[K*D] | cbT4[K*D] | flag_count | flag_list[N]
  char* ws = (char*)d_ws;
  float* c2 = (float*)ws;
  unsigned short* cbh = (unsigned short*)(ws + (size_t)K * 4);
  unsigned short* cbl = (unsigned short*)(ws + (size_t)K * 4 + (size_t)K * D * 2);
  float4* cbT4 = (float4*)(ws + (size_t)K * 4 + (size_t)K * D * 4);
  unsigned int* flag_count = (unsigned int*)(ws + (size_t)K * 4 + (size_t)K * D * 8);
  int* flag_list = (int*)(flag_count + 1);

  vq_prep<<<(K + 255) / 256, 256, 0, stream>>>(codebook, cbh, cbl, cbT4, c2,
                                               flag_count, K);

  vq_screen<<<N / 64, 256, 0, stream>>>(residual, codebook, cbh, cbl, c2,
                                        out_q, codes_f, flag_count, flag_list, N, K);

  vq_rescore<<<1024, 256, 0, stream>>>(residual, codebook, cbT4, c2, codes_f,
                                       out_q, flag_count, flag_list, K);
}